// Round 7
// baseline (7288.522 us; speedup 1.0000x reference)
//
#include <hip/hip_runtime.h>
#include <cmath>

#define VOCAB 32000
#define EMB   256
#define HID   512
#define TLEN  513      // SEQ + 1
#define G4    2048     // 4*HID
#define NREC  32       // recurrence blocks
#define NWORK 480      // persistent gemm worker blocks
#define GRID_TOTAL (NREC + NWORK)   // 512 = 2 blocks/CU capacity -> all resident
#define NTILE_T 5
#define NTILE_V 250
#define NTILES  (NTILE_T * NTILE_V)
#define SOS   1

typedef unsigned long long u64;
typedef unsigned int uivec4 __attribute__((ext_vector_type(4)));
typedef float f32x4 __attribute__((ext_vector_type(4)));

__device__ inline float fsig(float x)  { return __builtin_amdgcn_rcpf(1.f + __expf(-x)); }
__device__ inline float ftanh(float x) { return 1.f - 2.f * __builtin_amdgcn_rcpf(__expf(2.f * x) + 1.f); }
__device__ inline float fma4(f32x4 w, f32x4 h, float a) {
    return fmaf(w[0], h[0], fmaf(w[1], h[1], fmaf(w[2], h[2], fmaf(w[3], h[3], a))));
}

// ---------------------------------------------------------------------------
// Kernel A: Xg[t][r] = W_ih[r] . emb[tok_t] + b_ih[r] + b_hh[r]   (proven)
// ---------------------------------------------------------------------------
__global__ __launch_bounds__(256) void precompute_gates(
    const int* __restrict__ seq, const float* __restrict__ emb,
    const float* __restrict__ W_ih, const float* __restrict__ b_ih,
    const float* __restrict__ b_hh, float* __restrict__ Xg)
{
    __shared__ __align__(16) float ebuf[16][EMB];
    const int bt = blockIdx.x;   // 0..32
    const int br = blockIdx.y;   // 0..7
    const int tid = threadIdx.x;

    for (int tt = 0; tt < 16; ++tt) {
        int t = bt * 16 + tt;
        if (t < TLEN) {
            int tok = (t == 0) ? SOS : seq[t - 1];
            ebuf[tt][tid] = emb[(size_t)tok * EMB + tid];
        }
    }
    __syncthreads();

    const int row = br * 256 + tid;
    float acc[16];
#pragma unroll
    for (int tt = 0; tt < 16; ++tt) acc[tt] = 0.f;

    const float4* wp = (const float4*)(W_ih + (size_t)row * EMB);
#pragma unroll 4
    for (int k4 = 0; k4 < EMB / 4; ++k4) {
        float4 w = wp[k4];
#pragma unroll
        for (int tt = 0; tt < 16; ++tt) {
            float4 e = *(const float4*)&ebuf[tt][k4 * 4];
            acc[tt] = fmaf(w.x, e.x, fmaf(w.y, e.y, fmaf(w.z, e.z, fmaf(w.w, e.w, acc[tt]))));
        }
    }

    const float bias = b_ih[row] + b_hh[row];
    for (int tt = 0; tt < 16; ++tt) {
        int t = bt * 16 + tt;
        if (t < TLEN) Xg[(size_t)t * G4 + row] = acc[tt] + bias;
    }
}

// ---------------------------------------------------------------------------
// Mega kernel: blocks 0..31 = persistent LSTM recurrence (barrier-free);
// blocks 32..511 = persistent GEMM workers pulling tiles from a queue.
// All 512 blocks are co-resident (2/CU: VGPR<=256, LDS 36.9KB) -> no
// scheduling-order assumptions. All cross-block data flows through tagged
// u64 words (tag|payload in one 8B single-copy-atomic word) via MALL
// (sc0 sc1 / agent-scope) — the transport proven in rounds 2-6.
// ---------------------------------------------------------------------------
__global__ __launch_bounds__(256, 2) void mega(
    const float* __restrict__ Xg, const float* __restrict__ W_hh,
    const float* __restrict__ h0, const float* __restrict__ c0,
    const float* __restrict__ W_out, const float* __restrict__ b_out,
    u64* hs_tag, int* ready, int* wq,
    float* __restrict__ out, float* __restrict__ out_hT, float* __restrict__ out_cT)
{
    __shared__ __align__(16) char smem[2 * 128 * 36 * 4];  // gemm As+Bs; rec uses 8.5KB
    __shared__ int s_idx;
    const int tid = threadIdx.x;

    if (blockIdx.x < NREC) {
        // ================= recurrence role =================
        const int wg = blockIdx.x;
        const int w  = tid >> 6;        // wave 0..3
        const int ln = tid & 63;
        const int r  = ln >> 2;         // 0..15: local row
        const int q  = r >> 2;          // gate i,f,g,o
        const int jj = 4 * w + (r & 3); // h index within this block's 16
        const int ks = ln & 3;          // k quarter (128 cols)
        const int row = q * HID + wg * 16 + jj;

        float* hb = (float*)smem + w * 532;   // per-wave h copy, 4 regions of 132

        // W_hh[row][ks*128 .. +128) -> 32 pinned f32x4 (128 VGPRs)
        const f32x4* wp4 = (const f32x4*)(W_hh + (size_t)row * HID + ks * 128);
        f32x4 w00=wp4[0],  w01=wp4[1],  w02=wp4[2],  w03=wp4[3];
        f32x4 w04=wp4[4],  w05=wp4[5],  w06=wp4[6],  w07=wp4[7];
        f32x4 w08=wp4[8],  w09=wp4[9],  w10=wp4[10], w11=wp4[11];
        f32x4 w12=wp4[12], w13=wp4[13], w14=wp4[14], w15=wp4[15];
        f32x4 w16=wp4[16], w17=wp4[17], w18=wp4[18], w19=wp4[19];
        f32x4 w20=wp4[20], w21=wp4[21], w22=wp4[22], w23=wp4[23];
        f32x4 w24=wp4[24], w25=wp4[25], w26=wp4[26], w27=wp4[27];
        f32x4 w28=wp4[28], w29=wp4[29], w30=wp4[30], w31=wp4[31];
        asm volatile("" : "+v"(w00), "+v"(w01), "+v"(w02), "+v"(w03));
        asm volatile("" : "+v"(w04), "+v"(w05), "+v"(w06), "+v"(w07));
        asm volatile("" : "+v"(w08), "+v"(w09), "+v"(w10), "+v"(w11));
        asm volatile("" : "+v"(w12), "+v"(w13), "+v"(w14), "+v"(w15));
        asm volatile("" : "+v"(w16), "+v"(w17), "+v"(w18), "+v"(w19));
        asm volatile("" : "+v"(w20), "+v"(w21), "+v"(w22), "+v"(w23));
        asm volatile("" : "+v"(w24), "+v"(w25), "+v"(w26), "+v"(w27));
        asm volatile("" : "+v"(w28), "+v"(w29), "+v"(w30), "+v"(w31));

        // this lane's 8 polled h words and their LDS home
        const int wl  = 8 * ln;            // h element base
        float* wrp = hb + (wl >> 7) * 132 + (wl & 127);

        float c = (ln < 16) ? c0[wg * 16 + jj] : 0.f;

        {   // h_{-1} = h0
            float4 ha = *(const float4*)&h0[wl];
            float4 hc = *(const float4*)&h0[wl + 4];
            *(float4*)wrp = ha; *(float4*)(wrp + 4) = hc;
        }

        for (int t = 0; t < TLEN; ++t) {
            float xg = Xg[(size_t)t * G4 + row];   // issued before poll

            if (t > 0) {
                const unsigned tt = (unsigned)t;
                u64 a0 = (u64)(uintptr_t)(hs_tag + (size_t)(t - 1) * HID + wl);
                uivec4 r0, r1, r2, r3;
                for (;;) {
                    asm volatile(
                        "global_load_dwordx4 %0, %4, off sc0 sc1\n\t"
                        "global_load_dwordx4 %1, %4, off offset:16 sc0 sc1\n\t"
                        "global_load_dwordx4 %2, %4, off offset:32 sc0 sc1\n\t"
                        "global_load_dwordx4 %3, %4, off offset:48 sc0 sc1\n\t"
                        "s_waitcnt vmcnt(0)"
                        : "=&v"(r0), "=&v"(r1), "=&v"(r2), "=&v"(r3)
                        : "v"(a0));
                    if (r0.y == tt && r0.w == tt && r1.y == tt && r1.w == tt &&
                        r2.y == tt && r2.w == tt && r3.y == tt && r3.w == tt) break;
                }
                float4 f0 = { __uint_as_float(r0.x), __uint_as_float(r0.z),
                              __uint_as_float(r1.x), __uint_as_float(r1.z) };
                float4 f1 = { __uint_as_float(r2.x), __uint_as_float(r2.z),
                              __uint_as_float(r3.x), __uint_as_float(r3.z) };
                *(float4*)wrp = f0; *(float4*)(wrp + 4) = f1;
            }

            // full-row matvec over this lane's k-quarter (same-wave LDS, no barrier)
            const f32x4* hp = (const f32x4*)(hb + ks * 132);
            float a0 = 0.f, a1 = 0.f, a2 = 0.f, a3 = 0.f;
            a0 = fma4(w00, hp[0],  a0); a1 = fma4(w01, hp[1],  a1);
            a2 = fma4(w02, hp[2],  a2); a3 = fma4(w03, hp[3],  a3);
            a0 = fma4(w04, hp[4],  a0); a1 = fma4(w05, hp[5],  a1);
            a2 = fma4(w06, hp[6],  a2); a3 = fma4(w07, hp[7],  a3);
            a0 = fma4(w08, hp[8],  a0); a1 = fma4(w09, hp[9],  a1);
            a2 = fma4(w10, hp[10], a2); a3 = fma4(w11, hp[11], a3);
            a0 = fma4(w12, hp[12], a0); a1 = fma4(w13, hp[13], a1);
            a2 = fma4(w14, hp[14], a2); a3 = fma4(w15, hp[15], a3);
            a0 = fma4(w16, hp[16], a0); a1 = fma4(w17, hp[17], a1);
            a2 = fma4(w18, hp[18], a2); a3 = fma4(w19, hp[19], a3);
            a0 = fma4(w20, hp[20], a0); a1 = fma4(w21, hp[21], a1);
            a2 = fma4(w22, hp[22], a2); a3 = fma4(w23, hp[23], a3);
            a0 = fma4(w24, hp[24], a0); a1 = fma4(w25, hp[25], a1);
            a2 = fma4(w26, hp[26], a2); a3 = fma4(w27, hp[27], a3);
            a0 = fma4(w28, hp[28], a0); a1 = fma4(w29, hp[29], a1);
            a2 = fma4(w30, hp[30], a2); a3 = fma4(w31, hp[31], a3);
            float p = (a0 + a1) + (a2 + a3);

            // reduce across the 4 k-quarter lanes (in-wave)
            p += __shfl_xor(p, 1, 64);
            p += __shfl_xor(p, 2, 64);
            p += xg;

            float v = (q == 2) ? ftanh(p) : fsig(p);
            float f_ = __shfl(v, ln + 16, 64);
            float g_ = __shfl(v, ln + 32, 64);
            float o_ = __shfl(v, ln + 48, 64);

            if (ln < 16) {   // q==0 lanes: v = input gate
                c = fmaf(f_, c, v * g_);
                float h_ = o_ * ftanh(c);
                if ((ln & 3) == 0) {
                    u64 word = ((u64)(unsigned)(t + 1) << 32) | (u64)__float_as_uint(h_);
                    __hip_atomic_store(&hs_tag[(size_t)t * HID + wg * 16 + jj], word,
                                       __ATOMIC_RELAXED, __HIP_MEMORY_SCOPE_AGENT);
                    if (t == TLEN - 1) {
                        out_hT[wg * 16 + jj] = h_;
                        out_cT[wg * 16 + jj] = c;
                    }
                }
            }
            if (tid == 0 && (t == 127 || t == 255 || t == 383 || t == 511 || t == 512)) {
                __hip_atomic_fetch_add(&ready[t >> 7], 1,
                                       __ATOMIC_RELEASE, __HIP_MEMORY_SCOPE_AGENT);
            }
        }
    } else {
        // ================= gemm worker role =================
        float (*As)[36] = (float(*)[36])smem;
        float (*Bs)[36] = (float(*)[36])(smem + 128 * 36 * 4);
        const int tx = tid & 15, ty = tid >> 4;

        for (;;) {
            if (tid == 0)
                s_idx = __hip_atomic_fetch_add(wq, 1, __ATOMIC_RELAXED, __HIP_MEMORY_SCOPE_AGENT);
            __syncthreads();
            const int idx = s_idx;
            if (idx >= NTILES) break;
            const int tb = idx / NTILE_V;        // slow dim: tb 0..3 drain first
            const int vb = idx % NTILE_V;

            if (tid == 0) {
                while (__hip_atomic_load(&ready[tb], __ATOMIC_ACQUIRE,
                                         __HIP_MEMORY_SCOPE_AGENT) < NREC)
                    __builtin_amdgcn_s_sleep(16);
            }
            __syncthreads();

            const int m0 = tb * 128, n0 = vb * 128;
            float acc[8][8];
#pragma unroll
            for (int i = 0; i < 8; ++i)
#pragma unroll
                for (int jjj = 0; jjj < 8; ++jjj) acc[i][jjj] = 0.f;

            for (int k0 = 0; k0 < HID; k0 += 32) {
                // A tile from tagged hs words (tag == row+1 is the truth)
#pragma unroll
                for (int it = 0; it < 8; ++it) {
                    int li = tid + it * 256;     // 0..2047
                    int m  = li >> 4;            // row 0..127
                    int kp = li & 15;            // u64 pair index
                    int trow = m0 + m;
                    float2 fv = make_float2(0.f, 0.f);
                    if (trow < TLEN) {
                        u64 ap = (u64)(uintptr_t)(hs_tag + (size_t)trow * HID + k0 + kp * 2);
                        unsigned tg = (unsigned)(trow + 1);
                        uivec4 pr;
                        for (;;) {
                            asm volatile("global_load_dwordx4 %0, %1, off sc0 sc1\n\t"
                                         "s_waitcnt vmcnt(0)" : "=v"(pr) : "v"(ap));
                            if (pr.y == tg && pr.w == tg) break;
                            __builtin_amdgcn_s_sleep(1);
                        }
                        fv.x = __uint_as_float(pr.x);
                        fv.y = __uint_as_float(pr.z);
                    }
                    *(float2*)&As[m][kp * 2] = fv;
                }
#pragma unroll
                for (int it = 0; it < 4; ++it) {
                    int li = tid + it * 256;     // 0..1023
                    int m  = li >> 3;
                    int kq = li & 7;
                    float4 fb = *(const float4*)&W_out[(size_t)(n0 + m) * HID + k0 + kq * 4];
                    *(float4*)&Bs[m][kq * 4] = fb;
                }
                __syncthreads();

#pragma unroll
                for (int k4 = 0; k4 < 8; ++k4) {
                    float4 a4[8], b4[8];
#pragma unroll
                    for (int i = 0; i < 8; ++i) a4[i] = *(const float4*)&As[ty + 16 * i][k4 * 4];
#pragma unroll
                    for (int jjj = 0; jjj < 8; ++jjj) b4[jjj] = *(const float4*)&Bs[tx + 16 * jjj][k4 * 4];
#pragma unroll
                    for (int i = 0; i < 8; ++i)
#pragma unroll
                        for (int jjj = 0; jjj < 8; ++jjj) {
                            acc[i][jjj] = fmaf(a4[i].x, b4[jjj].x,
                                          fmaf(a4[i].y, b4[jjj].y,
                                          fmaf(a4[i].z, b4[jjj].z,
                                          fmaf(a4[i].w, b4[jjj].w, acc[i][jjj]))));
                        }
                }
                __syncthreads();
            }

#pragma unroll
            for (int jjj = 0; jjj < 8; ++jjj) {
                int vcol = n0 + tx + 16 * jjj;
                float bo = b_out[vcol];
#pragma unroll
                for (int i = 0; i < 8; ++i) {
                    int trow = m0 + ty + 16 * i;
                    if (trow < TLEN) out[(size_t)trow * VOCAB + vcol] = acc[i][jjj] + bo;
                }
            }
        }
    }
}

// ---------------------------------------------------------------------------
extern "C" void kernel_launch(void* const* d_in, const int* in_sizes, int n_in,
                              void* d_out, int out_size, void* d_ws, size_t ws_size,
                              hipStream_t stream)
{
    const int*   seq   = (const int*)  d_in[0];
    const float* h0    = (const float*)d_in[1];
    const float* c0    = (const float*)d_in[2];
    const float* emb   = (const float*)d_in[3];
    const float* W_ih  = (const float*)d_in[4];
    const float* W_hh  = (const float*)d_in[5];
    const float* b_ih  = (const float*)d_in[6];
    const float* b_hh  = (const float*)d_in[7];
    const float* W_out = (const float*)d_in[8];
    const float* b_out = (const float*)d_in[9];

    float* out_logits = (float*)d_out;                      // [513][32000]
    float* out_hT     = out_logits + (size_t)TLEN * VOCAB;  // [512]
    float* out_cT     = out_hT + HID;                       // [512]

    float* Xg     = (float*)d_ws;                     // 513*2048 f  (4.20 MB)
    u64*   hs_tag = (u64*)(Xg + (size_t)TLEN * G4);   // 513*512 u64 (2.10 MB)
    int*   ready  = (int*)(hs_tag + (size_t)TLEN * HID);  // [8]
    int*   wq     = ready + 8;                        // [1]

    // zero tags + counters every launch (replay-deterministic, kills any
    // first-call garbage that could alias a valid tag)
    hipMemsetAsync(hs_tag, 0, (size_t)TLEN * HID * sizeof(u64) + 64, stream);
    precompute_gates<<<dim3(33, 8), 256, 0, stream>>>(seq, emb, W_ih, b_ih, b_hh, Xg);
    mega<<<GRID_TOTAL, 256, 0, stream>>>(Xg, W_hh, h0, c0, W_out, b_out,
                                         hs_tag, ready, wq,
                                         out_logits, out_hT, out_cT);
}

// Round 8
// 1073.198 us; speedup vs baseline: 6.7914x; 6.7914x over previous
//
#include <hip/hip_runtime.h>
#include <cmath>

#define VOCAB 32000
#define EMB   256
#define HID   512
#define TLEN  513      // SEQ + 1
#define G4    2048     // 4*HID
#define NWG   32       // recurrence workgroups
#define SOS   1

typedef unsigned long long u64;
typedef unsigned int uivec4 __attribute__((ext_vector_type(4)));
typedef float f32x4 __attribute__((ext_vector_type(4)));
typedef short bf16x8 __attribute__((ext_vector_type(8)));

__device__ inline float fsig(float x)  { return __builtin_amdgcn_rcpf(1.f + __expf(-x)); }
__device__ inline float ftanh(float x) { return 1.f - 2.f * __builtin_amdgcn_rcpf(__expf(2.f * x) + 1.f); }

// split fp32 -> bf16 hi + bf16 lo (RNE both); x ~= hi + lo to ~2^-18 rel
__device__ inline void bf16split(float f, short& h, short& l) {
    unsigned u = __float_as_uint(f);
    unsigned r = u + (0x7fffu + ((u >> 16) & 1u));
    unsigned hb = r & 0xffff0000u;
    h = (short)(hb >> 16);
    float res = f - __uint_as_float(hb);
    unsigned u2 = __float_as_uint(res);
    unsigned r2 = u2 + (0x7fffu + ((u2 >> 16) & 1u));
    l = (short)(r2 >> 16);
}

// ---------------------------------------------------------------------------
// Kernel A: Xg[t][r] = W_ih[r] . emb[tok_t] + b_ih[r] + b_hh[r]   (proven)
// ---------------------------------------------------------------------------
__global__ __launch_bounds__(256) void precompute_gates(
    const int* __restrict__ seq, const float* __restrict__ emb,
    const float* __restrict__ W_ih, const float* __restrict__ b_ih,
    const float* __restrict__ b_hh, float* __restrict__ Xg)
{
    __shared__ __align__(16) float ebuf[16][EMB];
    const int bt = blockIdx.x;   // 0..32
    const int br = blockIdx.y;   // 0..7
    const int tid = threadIdx.x;

    for (int tt = 0; tt < 16; ++tt) {
        int t = bt * 16 + tt;
        if (t < TLEN) {
            int tok = (t == 0) ? SOS : seq[t - 1];
            ebuf[tt][tid] = emb[(size_t)tok * EMB + tid];
        }
    }
    __syncthreads();

    const int row = br * 256 + tid;
    float acc[16];
#pragma unroll
    for (int tt = 0; tt < 16; ++tt) acc[tt] = 0.f;

    const float4* wp = (const float4*)(W_ih + (size_t)row * EMB);
#pragma unroll 4
    for (int k4 = 0; k4 < EMB / 4; ++k4) {
        float4 w = wp[k4];
#pragma unroll
        for (int tt = 0; tt < 16; ++tt) {
            float4 e = *(const float4*)&ebuf[tt][k4 * 4];
            acc[tt] = fmaf(w.x, e.x, fmaf(w.y, e.y, fmaf(w.z, e.z, fmaf(w.w, e.w, acc[tt]))));
        }
    }

    const float bias = b_ih[row] + b_hh[row];
    for (int tt = 0; tt < 16; ++tt) {
        int t = bt * 16 + tt;
        if (t < TLEN) Xg[(size_t)t * G4 + row] = acc[tt] + bias;
    }
}

// ---------------------------------------------------------------------------
// Kernel B: persistent LSTM recurrence. 32 WGs x 256 threads (round-5 core).
// Transport: tag|float u64 words via MALL (sc0 sc1 loads / agent stores) —
// single-copy atomic, no fences, proven rounds 2-7. New: 2-slot pipelined
// poll (two dwordx4 in flight, vmcnt(1) waits) -> check granularity ~RTT/2.
// ---------------------------------------------------------------------------
__global__ __launch_bounds__(256, 1) void lstm_recurrence(
    const float* __restrict__ Xg, const float* __restrict__ W_hh,
    const float* __restrict__ h0, const float* __restrict__ c0,
    float* __restrict__ hs, u64* pk,
    float* __restrict__ out_hT, float* __restrict__ out_cT)
{
    __shared__ __align__(16) float hbuf[HID];
    __shared__ float pbuf[256];

    const int wg  = blockIdx.x;     // 0..31
    const int tid = threadIdx.x;
    const int wv  = tid >> 6;       // k segment 0..3
    const int ln  = tid & 63;
    const int q   = ln >> 4;        // gate i,f,g,o
    const int j   = ln & 15;
    const int row = q * HID + wg * 16 + j;

    float4 wreg[32];
    const float4* wp = (const float4*)(W_hh + (size_t)row * HID + wv * 128);
#pragma unroll
    for (int i = 0; i < 32; ++i) wreg[i] = wp[i];

    float c = (tid < 16) ? c0[wg * 16 + tid] : 0.f;
    {
        float2 h2 = *(const float2*)&h0[tid * 2];
        hbuf[tid * 2]     = h2.x;
        hbuf[tid * 2 + 1] = h2.y;
    }
    __syncthreads();

    for (int t = 0; t < TLEN; ++t) {
        // activation lanes' Xg (4 gate rows each), issued before the poll
        float xg0 = 0.f, xg1 = 0.f, xg2 = 0.f, xg3 = 0.f;
        if (tid < 16) {
            const float* xp = Xg + (size_t)t * G4 + wg * 16 + tid;
            xg0 = xp[0]; xg1 = xp[512]; xg2 = xp[1024]; xg3 = xp[1536];
        }

        if (t > 0) {
            const unsigned tt = (unsigned)t;
            u64 sa = (u64)(uintptr_t)(pk + (size_t)(t & 1) * HID + 2 * tid);
            // drain xg loads + previous-step stores so vmcnt counts only polls
            asm volatile("s_waitcnt vmcnt(0)" ::: "memory");
            uivec4 rA, rB;
            asm volatile("global_load_dwordx4 %0, %1, off sc0 sc1"
                         : "=v"(rA) : "v"(sa));
            asm volatile("global_load_dwordx4 %0, %1, off sc0 sc1\n\t"
                         "s_waitcnt vmcnt(1)"
                         : "=v"(rB) : "v"(sa));
            unsigned w0, w1;
            for (;;) {
                if (rA.y == tt && rA.w == tt) { w0 = rA.x; w1 = rA.z; break; }
                asm volatile("global_load_dwordx4 %0, %1, off sc0 sc1\n\t"
                             "s_waitcnt vmcnt(1)"
                             : "=v"(rA) : "v"(sa));
                if (rB.y == tt && rB.w == tt) { w0 = rB.x; w1 = rB.z; break; }
                asm volatile("global_load_dwordx4 %0, %1, off sc0 sc1\n\t"
                             "s_waitcnt vmcnt(1)"
                             : "=v"(rB) : "v"(sa));
            }
            // drain the still-in-flight slot before its register can be reused
            asm volatile("s_waitcnt vmcnt(0)" : : "v"(rA), "v"(rB));
            hbuf[2 * tid]     = __uint_as_float(w0);
            hbuf[2 * tid + 1] = __uint_as_float(w1);
            __syncthreads();                                  // B1
        }

        // partial matvec (hbuf reads are full-wave broadcasts: conflict-free)
        float acc8[8];
#pragma unroll
        for (int i = 0; i < 8; ++i) acc8[i] = 0.f;
#pragma unroll
        for (int i = 0; i < 32; ++i) {
            float4 w4 = wreg[i];
            float4 h4 = *(const float4*)&hbuf[wv * 128 + i * 4];
            acc8[i & 7] = fmaf(w4.x, h4.x, fmaf(w4.y, h4.y,
                          fmaf(w4.z, h4.z, fmaf(w4.w, h4.w, acc8[i & 7]))));
        }
        pbuf[tid] = ((acc8[0] + acc8[1]) + (acc8[2] + acc8[3]))
                  + ((acc8[4] + acc8[5]) + (acc8[6] + acc8[7]));
        __syncthreads();                                      // B2

        if (tid < 16) {
            float gi = pbuf[tid]      + pbuf[64 + tid]  + pbuf[128 + tid] + pbuf[192 + tid] + xg0;
            float gf = pbuf[16 + tid] + pbuf[80 + tid]  + pbuf[144 + tid] + pbuf[208 + tid] + xg1;
            float gg = pbuf[32 + tid] + pbuf[96 + tid]  + pbuf[160 + tid] + pbuf[224 + tid] + xg2;
            float go = pbuf[48 + tid] + pbuf[112 + tid] + pbuf[176 + tid] + pbuf[240 + tid] + xg3;
            float i_ = fsig(gi);
            float f_ = fsig(gf);
            float g_ = ftanh(gg);
            float o_ = fsig(go);
            c = fmaf(f_, c, i_ * g_);
            float h_ = o_ * ftanh(c);
            if (t < TLEN - 1) {   // publish FIRST (latency-critical), hs after
                u64 word = ((u64)(unsigned)(t + 1) << 32) | (u64)__float_as_uint(h_);
                __hip_atomic_store(&pk[(size_t)((t + 1) & 1) * HID + wg * 16 + tid], word,
                                   __ATOMIC_RELAXED, __HIP_MEMORY_SCOPE_AGENT);
            } else {
                out_hT[wg * 16 + tid] = h_;
                out_cT[wg * 16 + tid] = c;
            }
            hs[(size_t)t * HID + wg * 16 + tid] = h_;
        }
    }
}

// ---------------------------------------------------------------------------
// Kernel C: out[t][v] = hs[t].W_out[v] + b_out[v]  via split-bf16 MFMA.
// x = hi + lo (bf16 each); A.B ~= Ah.Bh + Ah.Bl + Al.Bh (fp32 accum).
// Tile 128x128, BK=32, 4 waves (each: 2 row-tiles x 8 col-tiles of 16x16),
// 3 MFMAs per tile per K-step. Frag layout (m91/m97-verified pattern):
//   A: lane l -> hs[m0+(l&15)][k0+8*(l>>4)+e]   (8 contiguous k)
//   B: lane l -> W_out[n0+(l&15)][k0+8*(l>>4)+e]
//   D: col = l&15, row = (l>>4)*4 + reg
// LDS rows padded to 40 shorts (80B): 16B-aligned b128, 2-way banks (free).
// ---------------------------------------------------------------------------
#define GLDT 40

__global__ __launch_bounds__(256, 2) void out_gemm_mfma(
    const float* __restrict__ hs, const float* __restrict__ W_out,
    const float* __restrict__ b_out, float* __restrict__ out)
{
    __shared__ __align__(16) short Ah[128][GLDT];
    __shared__ __align__(16) short Al[128][GLDT];
    __shared__ __align__(16) short Bh[128][GLDT];
    __shared__ __align__(16) short Bl[128][GLDT];

    const int tb = blockIdx.x;     // 0..4   (time tiles)
    const int vb = blockIdx.y;     // 0..249 (vocab tiles)
    const int tid = threadIdx.x;
    const int w   = tid >> 6;      // wave 0..3
    const int l   = tid & 63;
    const int l15 = l & 15;
    const int lg  = l >> 4;
    const int m0 = tb * 128, n0 = vb * 128;

    // staging role: row r = tid>>1, k-half kh = (tid&1)*16
    const int sr = tid >> 1;
    const int kh = (tid & 1) * 16;

    f32x4 acc[2][8];
#pragma unroll
    for (int s = 0; s < 2; ++s)
#pragma unroll
        for (int cc = 0; cc < 8; ++cc) acc[s][cc] = (f32x4){0.f, 0.f, 0.f, 0.f};

    for (int k0 = 0; k0 < HID; k0 += 32) {
        // ---- stage + convert A (hs rows) ----
        {
            int trow = m0 + sr;
            float4 fa0 = make_float4(0.f,0.f,0.f,0.f), fa1 = fa0, fa2 = fa0, fa3 = fa0;
            if (trow < TLEN) {
                const float4* ap = (const float4*)(hs + (size_t)trow * HID + k0 + kh);
                fa0 = ap[0]; fa1 = ap[1]; fa2 = ap[2]; fa3 = ap[3];
            }
            float fv[16] = { fa0.x,fa0.y,fa0.z,fa0.w, fa1.x,fa1.y,fa1.z,fa1.w,
                             fa2.x,fa2.y,fa2.z,fa2.w, fa3.x,fa3.y,fa3.z,fa3.w };
#pragma unroll
            for (int g = 0; g < 2; ++g) {
                union { short s[8]; bf16x8 v; } ph, pl;
#pragma unroll
                for (int e = 0; e < 8; ++e) bf16split(fv[g * 8 + e], ph.s[e], pl.s[e]);
                *(bf16x8*)&Ah[sr][kh + 8 * g] = ph.v;
                *(bf16x8*)&Al[sr][kh + 8 * g] = pl.v;
            }
        }
        // ---- stage + convert B (W_out rows) ----
        {
            const float4* bp = (const float4*)(W_out + (size_t)(n0 + sr) * HID + k0 + kh);
            float4 fb0 = bp[0], fb1 = bp[1], fb2 = bp[2], fb3 = bp[3];
            float fv[16] = { fb0.x,fb0.y,fb0.z,fb0.w, fb1.x,fb1.y,fb1.z,fb1.w,
                             fb2.x,fb2.y,fb2.z,fb2.w, fb3.x,fb3.y,fb3.z,fb3.w };
#pragma unroll
            for (int g = 0; g < 2; ++g) {
                union { short s[8]; bf16x8 v; } ph, pl;
#pragma unroll
                for (int e = 0; e < 8; ++e) bf16split(fv[g * 8 + e], ph.s[e], pl.s[e]);
                *(bf16x8*)&Bh[sr][kh + 8 * g] = ph.v;
                *(bf16x8*)&Bl[sr][kh + 8 * g] = pl.v;
            }
        }
        __syncthreads();

        bf16x8 ah[2], al2[2];
#pragma unroll
        for (int s = 0; s < 2; ++s) {
            ah[s]  = *(const bf16x8*)&Ah[32 * w + 16 * s + l15][8 * lg];
            al2[s] = *(const bf16x8*)&Al[32 * w + 16 * s + l15][8 * lg];
        }
#pragma unroll
        for (int cc = 0; cc < 8; ++cc) {
            bf16x8 bh = *(const bf16x8*)&Bh[16 * cc + l15][8 * lg];
            bf16x8 bl = *(const bf16x8*)&Bl[16 * cc + l15][8 * lg];
#pragma unroll
            for (int s = 0; s < 2; ++s) {
                acc[s][cc] = __builtin_amdgcn_mfma_f32_16x16x32_bf16(ah[s],  bh, acc[s][cc], 0, 0, 0);
                acc[s][cc] = __builtin_amdgcn_mfma_f32_16x16x32_bf16(ah[s],  bl, acc[s][cc], 0, 0, 0);
                acc[s][cc] = __builtin_amdgcn_mfma_f32_16x16x32_bf16(al2[s], bh, acc[s][cc], 0, 0, 0);
            }
        }
        __syncthreads();
    }

#pragma unroll
    for (int cc = 0; cc < 8; ++cc) {
        int col = n0 + 16 * cc + l15;
        float bo = b_out[col];
#pragma unroll
        for (int s = 0; s < 2; ++s) {
            int rbase = m0 + 32 * w + 16 * s + lg * 4;
#pragma unroll
            for (int r = 0; r < 4; ++r) {
                int trow = rbase + r;
                if (trow < TLEN) out[(size_t)trow * VOCAB + col] = acc[s][cc][r] + bo;
            }
        }
    }
}

// ---------------------------------------------------------------------------
extern "C" void kernel_launch(void* const* d_in, const int* in_sizes, int n_in,
                              void* d_out, int out_size, void* d_ws, size_t ws_size,
                              hipStream_t stream)
{
    const int*   seq   = (const int*)  d_in[0];
    const float* h0    = (const float*)d_in[1];
    const float* c0    = (const float*)d_in[2];
    const float* emb   = (const float*)d_in[3];
    const float* W_ih  = (const float*)d_in[4];
    const float* W_hh  = (const float*)d_in[5];
    const float* b_ih  = (const float*)d_in[6];
    const float* b_hh  = (const float*)d_in[7];
    const float* W_out = (const float*)d_in[8];
    const float* b_out = (const float*)d_in[9];

    float* out_logits = (float*)d_out;                      // [513][32000]
    float* out_hT     = out_logits + (size_t)TLEN * VOCAB;  // [512]
    float* out_cT     = out_hT + HID;                       // [512]

    float* Xg = (float*)d_ws;                    // 513*2048 f
    float* hs = Xg + (size_t)TLEN * G4;          // 513*512 f
    u64*   pk = (u64*)(hs + (size_t)TLEN * HID); // [2][512] tag|h words

    hipMemsetAsync(pk, 0, 2 * HID * sizeof(u64), stream);
    precompute_gates<<<dim3(33, 8), 256, 0, stream>>>(seq, emb, W_ih, b_ih, b_hh, Xg);
    lstm_recurrence<<<NWG, 256, 0, stream>>>(Xg, W_hh, h0, c0, hs, pk, out_hT, out_cT);
    out_gemm_mfma<<<dim3(5, 250), 256, 0, stream>>>(hs, W_out, b_out, out_logits);
}

// Round 9
// 924.835 us; speedup vs baseline: 7.8809x; 1.1604x over previous
//
#include <hip/hip_runtime.h>
#include <cmath>

#define VOCAB 32000
#define EMB   256
#define HID   512
#define TLEN  513      // SEQ + 1
#define G4    2048     // 4*HID
#define NWG   32       // recurrence roles
#define SOS   1

typedef unsigned long long u64;
typedef unsigned int uivec4 __attribute__((ext_vector_type(4)));
typedef float f32x4 __attribute__((ext_vector_type(4)));
typedef short bf16x8 __attribute__((ext_vector_type(8)));

__device__ inline float fsig(float x)  { return __builtin_amdgcn_rcpf(1.f + __expf(-x)); }
__device__ inline float ftanh(float x) { return 1.f - 2.f * __builtin_amdgcn_rcpf(__expf(2.f * x) + 1.f); }

// split fp32 -> bf16 hi + bf16 lo (RNE both); x ~= hi + lo to ~2^-18 rel
__device__ inline void bf16split(float f, short& h, short& l) {
    unsigned u = __float_as_uint(f);
    unsigned r = u + (0x7fffu + ((u >> 16) & 1u));
    unsigned hb = r & 0xffff0000u;
    h = (short)(hb >> 16);
    float res = f - __uint_as_float(hb);
    unsigned u2 = __float_as_uint(res);
    unsigned r2 = u2 + (0x7fffu + ((u2 >> 16) & 1u));
    l = (short)(r2 >> 16);
}

// ---------------------------------------------------------------------------
// Kernel A: Xg[t][r] = W_ih[r] . emb[tok_t] + b_ih[r] + b_hh[r]   (proven)
// ---------------------------------------------------------------------------
__global__ __launch_bounds__(256) void precompute_gates(
    const int* __restrict__ seq, const float* __restrict__ emb,
    const float* __restrict__ W_ih, const float* __restrict__ b_ih,
    const float* __restrict__ b_hh, float* __restrict__ Xg)
{
    __shared__ __align__(16) float ebuf[16][EMB];
    const int bt = blockIdx.x;   // 0..32
    const int br = blockIdx.y;   // 0..7
    const int tid = threadIdx.x;

    for (int tt = 0; tt < 16; ++tt) {
        int t = bt * 16 + tt;
        if (t < TLEN) {
            int tok = (t == 0) ? SOS : seq[t - 1];
            ebuf[tt][tid] = emb[(size_t)tok * EMB + tid];
        }
    }
    __syncthreads();

    const int row = br * 256 + tid;
    float acc[16];
#pragma unroll
    for (int tt = 0; tt < 16; ++tt) acc[tt] = 0.f;

    const float4* wp = (const float4*)(W_ih + (size_t)row * EMB);
#pragma unroll 4
    for (int k4 = 0; k4 < EMB / 4; ++k4) {
        float4 w = wp[k4];
#pragma unroll
        for (int tt = 0; tt < 16; ++tt) {
            float4 e = *(const float4*)&ebuf[tt][k4 * 4];
            acc[tt] = fmaf(w.x, e.x, fmaf(w.y, e.y, fmaf(w.z, e.z, fmaf(w.w, e.w, acc[tt]))));
        }
    }

    const float bias = b_ih[row] + b_hh[row];
    for (int tt = 0; tt < 16; ++tt) {
        int t = bt * 16 + tt;
        if (t < TLEN) Xg[(size_t)t * G4 + row] = acc[tt] + bias;
    }
}

// ---------------------------------------------------------------------------
// Kernel B: persistent LSTM recurrence. Roles = blocks with blockIdx%8==0
// (wg = blockIdx/8) -> under round-robin dispatch these share ONE XCD L2.
// Transport: tag|float u64 words, tag+payload in one 8B single-copy-atomic
// word (no fences). Two physical paths:
//   fast: pf[] via sc0 store/load through the (assumed) shared XCD L2,
//         bounded K polls; per-wave EVERY-STEP ballot -> any exhaustion
//         flips the wave to slow forever (wrong placement costs ~2 steps).
//   slow: pk[] via MALL (sc0 sc1 / agent atomics) - proven rounds 2-8,
//         unbounded but guaranteed-progress.
// Barrier B1 removed: wave wv polls words [128wv,128wv+128) and its matvec
// reads exactly hbuf[128wv..128wv+128) - wave-local, in-order LDS.
// pbuf double-buffered so the single remaining barrier per step suffices.
// ---------------------------------------------------------------------------
__global__ __launch_bounds__(256, 1) void lstm_recurrence(
    const float* __restrict__ Xg, const float* __restrict__ W_hh,
    const float* __restrict__ h0, const float* __restrict__ c0,
    float* __restrict__ hs, u64* pk, u64* pf,
    float* __restrict__ out_hT, float* __restrict__ out_cT)
{
    __shared__ __align__(16) float hbuf[HID];
    __shared__ float pbuf[2][256];

    const int bx = blockIdx.x;
    if (bx & 7) return;             // keep only blocks 0,8,...,248
    const int wg  = bx >> 3;        // 0..31
    const int tid = threadIdx.x;
    const int wv  = tid >> 6;       // k segment 0..3
    const int ln  = tid & 63;
    const int q   = ln >> 4;        // gate i,f,g,o
    const int j   = ln & 15;
    const int row = q * HID + wg * 16 + j;

    float4 wreg[32];
    const float4* wp = (const float4*)(W_hh + (size_t)row * HID + wv * 128);
#pragma unroll
    for (int i = 0; i < 32; ++i) wreg[i] = wp[i];

    float c = (tid < 16) ? c0[wg * 16 + tid] : 0.f;
    {
        float2 h2 = *(const float2*)&h0[tid * 2];
        hbuf[tid * 2]     = h2.x;
        hbuf[tid * 2 + 1] = h2.y;
    }
    __syncthreads();

    bool usefast = true;            // per-wave (ballot keeps it uniform)

    for (int t = 0; t < TLEN; ++t) {
        // activation lanes' Xg (4 gate rows each), issued before the poll
        float xg0 = 0.f, xg1 = 0.f, xg2 = 0.f, xg3 = 0.f;
        if (tid < 16) {
            const float* xp = Xg + (size_t)t * G4 + wg * 16 + tid;
            xg0 = xp[0]; xg1 = xp[512]; xg2 = xp[1024]; xg3 = xp[1536];
        }

        if (t > 0) {
            const unsigned tt = (unsigned)t;
            const size_t off = (size_t)(t & 1) * HID + 2 * tid;
            uivec4 r;
            bool got = false;
            if (usefast) {          // bounded XCD-L2 phase
                u64 fa = (u64)(uintptr_t)(pf + off);
                const int K = (t == 1) ? 128 : 64;
                for (int it = 0; it < K; ++it) {
                    asm volatile("global_load_dwordx4 %0, %1, off sc0\n\t"
                                 "s_waitcnt vmcnt(0)" : "=v"(r) : "v"(fa));
                    if (r.y == tt && r.w == tt) { got = true; break; }
                }
                if (__ballot(got ? 1 : 0) != ~0ull) usefast = false;  // sticky
            }
            if (!got) {             // guaranteed MALL path (proven)
                u64 sa = (u64)(uintptr_t)(pk + off);
                do {
                    asm volatile("global_load_dwordx4 %0, %1, off sc0 sc1\n\t"
                                 "s_waitcnt vmcnt(0)" : "=v"(r) : "v"(sa));
                } while (r.y != tt || r.w != tt);
            }
            hbuf[2 * tid]     = __uint_as_float(r.x);
            hbuf[2 * tid + 1] = __uint_as_float(r.z);
            asm volatile("s_waitcnt lgkmcnt(0)" ::: "memory");
            // no barrier: this wave wrote exactly the slice it reads below
        }

        // partial matvec (hbuf reads are full-wave broadcasts: conflict-free)
        float acc8[8];
#pragma unroll
        for (int i = 0; i < 8; ++i) acc8[i] = 0.f;
#pragma unroll
        for (int i = 0; i < 32; ++i) {
            float4 w4 = wreg[i];
            float4 h4 = *(const float4*)&hbuf[wv * 128 + i * 4];
            acc8[i & 7] = fmaf(w4.x, h4.x, fmaf(w4.y, h4.y,
                          fmaf(w4.z, h4.z, fmaf(w4.w, h4.w, acc8[i & 7]))));
        }
        pbuf[t & 1][tid] = ((acc8[0] + acc8[1]) + (acc8[2] + acc8[3]))
                         + ((acc8[4] + acc8[5]) + (acc8[6] + acc8[7]));
        __syncthreads();                                  // the step's ONLY barrier

        if (tid < 16) {
            const float* pb = pbuf[t & 1];
            float gi = pb[tid]      + pb[64 + tid]  + pb[128 + tid] + pb[192 + tid] + xg0;
            float gf = pb[16 + tid] + pb[80 + tid]  + pb[144 + tid] + pb[208 + tid] + xg1;
            float gg = pb[32 + tid] + pb[96 + tid]  + pb[160 + tid] + pb[224 + tid] + xg2;
            float go = pb[48 + tid] + pb[112 + tid] + pb[176 + tid] + pb[240 + tid] + xg3;
            float i_ = fsig(gi);
            float f_ = fsig(gf);
            float g_ = ftanh(gg);
            float o_ = fsig(go);
            c = fmaf(f_, c, i_ * g_);
            float h_ = o_ * ftanh(c);
            if (t < TLEN - 1) {     // publish fast word first, then MALL truth
                u64 word = ((u64)(unsigned)(t + 1) << 32) | (u64)__float_as_uint(h_);
                size_t po = (size_t)((t + 1) & 1) * HID + wg * 16 + tid;
                u64 faddr = (u64)(uintptr_t)(pf + po);
                asm volatile("global_store_dwordx2 %0, %1, off sc0"
                             :: "v"(faddr), "v"(word) : "memory");
                __hip_atomic_store(&pk[po], word, __ATOMIC_RELAXED, __HIP_MEMORY_SCOPE_AGENT);
            } else {
                out_hT[wg * 16 + tid] = h_;
                out_cT[wg * 16 + tid] = c;
            }
            hs[(size_t)t * HID + wg * 16 + tid] = h_;
        }
        // pbuf hazard handled by double-buffer: step t+1 writes pbuf[(t+1)&1].
    }
}

// ---------------------------------------------------------------------------
// Kernel C: out[t][v] = hs[t].W_out[v] + b_out[v]  via split-bf16 MFMA.
// (proven round 8: x = hi+lo bf16; A.B ~= Ah.Bh + Ah.Bl + Al.Bh, fp32 accum)
// ---------------------------------------------------------------------------
#define GLDT 40

__global__ __launch_bounds__(256, 2) void out_gemm_mfma(
    const float* __restrict__ hs, const float* __restrict__ W_out,
    const float* __restrict__ b_out, float* __restrict__ out)
{
    __shared__ __align__(16) short Ah[128][GLDT];
    __shared__ __align__(16) short Al[128][GLDT];
    __shared__ __align__(16) short Bh[128][GLDT];
    __shared__ __align__(16) short Bl[128][GLDT];

    const int tb = blockIdx.x;     // 0..4   (time tiles)
    const int vb = blockIdx.y;     // 0..249 (vocab tiles)
    const int tid = threadIdx.x;
    const int w   = tid >> 6;      // wave 0..3
    const int l   = tid & 63;
    const int l15 = l & 15;
    const int lg  = l >> 4;
    const int m0 = tb * 128, n0 = vb * 128;

    const int sr = tid >> 1;
    const int kh = (tid & 1) * 16;

    f32x4 acc[2][8];
#pragma unroll
    for (int s = 0; s < 2; ++s)
#pragma unroll
        for (int cc = 0; cc < 8; ++cc) acc[s][cc] = (f32x4){0.f, 0.f, 0.f, 0.f};

    for (int k0 = 0; k0 < HID; k0 += 32) {
        {
            int trow = m0 + sr;
            float4 fa0 = make_float4(0.f,0.f,0.f,0.f), fa1 = fa0, fa2 = fa0, fa3 = fa0;
            if (trow < TLEN) {
                const float4* ap = (const float4*)(hs + (size_t)trow * HID + k0 + kh);
                fa0 = ap[0]; fa1 = ap[1]; fa2 = ap[2]; fa3 = ap[3];
            }
            float fv[16] = { fa0.x,fa0.y,fa0.z,fa0.w, fa1.x,fa1.y,fa1.z,fa1.w,
                             fa2.x,fa2.y,fa2.z,fa2.w, fa3.x,fa3.y,fa3.z,fa3.w };
#pragma unroll
            for (int g = 0; g < 2; ++g) {
                union { short s[8]; bf16x8 v; } ph, pl;
#pragma unroll
                for (int e = 0; e < 8; ++e) bf16split(fv[g * 8 + e], ph.s[e], pl.s[e]);
                *(bf16x8*)&Ah[sr][kh + 8 * g] = ph.v;
                *(bf16x8*)&Al[sr][kh + 8 * g] = pl.v;
            }
        }
        {
            const float4* bp = (const float4*)(W_out + (size_t)(n0 + sr) * HID + k0 + kh);
            float4 fb0 = bp[0], fb1 = bp[1], fb2 = bp[2], fb3 = bp[3];
            float fv[16] = { fb0.x,fb0.y,fb0.z,fb0.w, fb1.x,fb1.y,fb1.z,fb1.w,
                             fb2.x,fb2.y,fb2.z,fb2.w, fb3.x,fb3.y,fb3.z,fb3.w };
#pragma unroll
            for (int g = 0; g < 2; ++g) {
                union { short s[8]; bf16x8 v; } ph, pl;
#pragma unroll
                for (int e = 0; e < 8; ++e) bf16split(fv[g * 8 + e], ph.s[e], pl.s[e]);
                *(bf16x8*)&Bh[sr][kh + 8 * g] = ph.v;
                *(bf16x8*)&Bl[sr][kh + 8 * g] = pl.v;
            }
        }
        __syncthreads();

        bf16x8 ah[2], al2[2];
#pragma unroll
        for (int s = 0; s < 2; ++s) {
            ah[s]  = *(const bf16x8*)&Ah[32 * w + 16 * s + l15][8 * lg];
            al2[s] = *(const bf16x8*)&Al[32 * w + 16 * s + l15][8 * lg];
        }
#pragma unroll
        for (int cc = 0; cc < 8; ++cc) {
            bf16x8 bh = *(const bf16x8*)&Bh[16 * cc + l15][8 * lg];
            bf16x8 bl = *(const bf16x8*)&Bl[16 * cc + l15][8 * lg];
#pragma unroll
            for (int s = 0; s < 2; ++s) {
                acc[s][cc] = __builtin_amdgcn_mfma_f32_16x16x32_bf16(ah[s],  bh, acc[s][cc], 0, 0, 0);
                acc[s][cc] = __builtin_amdgcn_mfma_f32_16x16x32_bf16(ah[s],  bl, acc[s][cc], 0, 0, 0);
                acc[s][cc] = __builtin_amdgcn_mfma_f32_16x16x32_bf16(al2[s], bh, acc[s][cc], 0, 0, 0);
            }
        }
        __syncthreads();
    }

#pragma unroll
    for (int cc = 0; cc < 8; ++cc) {
        int col = n0 + 16 * cc + l15;
        float bo = b_out[col];
#pragma unroll
        for (int s = 0; s < 2; ++s) {
            int rbase = m0 + 32 * w + 16 * s + lg * 4;
#pragma unroll
            for (int r = 0; r < 4; ++r) {
                int trow = rbase + r;
                if (trow < TLEN) out[(size_t)trow * VOCAB + col] = acc[s][cc][r] + bo;
            }
        }
    }
}

// ---------------------------------------------------------------------------
extern "C" void kernel_launch(void* const* d_in, const int* in_sizes, int n_in,
                              void* d_out, int out_size, void* d_ws, size_t ws_size,
                              hipStream_t stream)
{
    const int*   seq   = (const int*)  d_in[0];
    const float* h0    = (const float*)d_in[1];
    const float* c0    = (const float*)d_in[2];
    const float* emb   = (const float*)d_in[3];
    const float* W_ih  = (const float*)d_in[4];
    const float* W_hh  = (const float*)d_in[5];
    const float* b_ih  = (const float*)d_in[6];
    const float* b_hh  = (const float*)d_in[7];
    const float* W_out = (const float*)d_in[8];
    const float* b_out = (const float*)d_in[9];

    float* out_logits = (float*)d_out;                      // [513][32000]
    float* out_hT     = out_logits + (size_t)TLEN * VOCAB;  // [512]
    float* out_cT     = out_hT + HID;                       // [512]

    float* Xg = (float*)d_ws;                    // 513*2048 f
    float* hs = Xg + (size_t)TLEN * G4;          // 513*512 f
    u64*   pk = (u64*)(hs + (size_t)TLEN * HID); // [2][512] MALL words
    u64*   pf = pk + 2 * HID;                    // [2][512] XCD-L2 words

    hipMemsetAsync(pk, 0, 4 * HID * sizeof(u64), stream);   // pk + pf
    precompute_gates<<<dim3(33, 8), 256, 0, stream>>>(seq, emb, W_ih, b_ih, b_hh, Xg);
    lstm_recurrence<<<249, 256, 0, stream>>>(Xg, W_hh, h0, c0, hs, pk, pf, out_hT, out_cT);
    out_gemm_mfma<<<dim3(5, 250), 256, 0, stream>>>(hs, W_out, b_out, out_logits);
}